// Round 11
// baseline (319.047 us; speedup 1.0000x reference)
//
#include <hip/hip_runtime.h>

#define NB 1000000
#define NA 40
#define TILE 256
#define NTILES ((NB + TILE - 1) / TILE)   // 3907
#define NEG_LN2_OVER_A (-0.017328679513998632f)  // -ln(2)/40, folded into weights
#define F_NORM 14   // attr rows [0,14): normal loads (LLC-resident, 56 MB);
                    // rows [14,40): nt (stream from HBM, 104 MB).
                    // LLC residency: inputs 160 + targets 56 = 216 MB < 256.

// R11: path-split A/B on the R10 base (93.9 us; R9 93.1).
// R10 killed the occupancy theory (48->64%, dur unchanged). State: targets
// 100% HBM at 1.70 TB/s, inputs 100% LLC at 1.70 TB/s (FETCH == targets
// exactly). The 1.7/1.7 equality is structural (lockstep consumption) — it
// hides which path is the straggler. Hypotheses:
//  H1 shared CU<->fabric read path caps ~3.4 TB/s -> re-balancing is neutral
//     -> 93 us is the roofline (declare next round).
//  H2 HBM/nt path caps ~1.7, LLC has headroom -> shifting 56 MB of targets
//     to LLC wins: HBM 104 MB/1.7 = 61 us -> dur 61-75 us.
//  H3 LLC path caps ~1.7, HBM has headroom -> dur RISES ~105-127 -> nt-both.
// Change vs R10: target rows a<14 load normal, a>=14 nt. Branch is
// wave-uniform (a = wave + 4j), zero divergence. Else byte-identical.
typedef int   ivec4 __attribute__((ext_vector_type(4)));

__global__ __launch_bounds__(256, 8) void focal_loss_kernel(
    const float* __restrict__ inputs,    // [NB, NA] f32
    const int*   __restrict__ targets,   // [NA, NB] i32 in {0,1}
    const float* __restrict__ attr_w,    // [NA] f32
    float* __restrict__ out)             // [1] f32 (pre-zeroed)
{
    __shared__ unsigned int s_t[NA * 65];      // [40][65] u32 = [40][260] bytes
    __shared__ float s_aw[NA];
    __shared__ float s_red[TILE / 64];

    const int t  = threadIdx.x;
    const int b0 = blockIdx.x * TILE;

    if (t < NA) s_aw[t] = attr_w[t] * NEG_LN2_OVER_A;

    float acc = 0.0f;

    if (blockIdx.x != NTILES - 1) {
        // ================= fast path: full tile, no per-element guards ======
        ivec4 v[10];
        #pragma unroll
        for (int j = 0; j < 10; ++j) {
            const int q  = t + TILE * j;   // [0, 2560)
            const int a  = q >> 6;         // attr 0..39 (= wave + 4j, wave-uniform)
            const int t4 = q & 63;         // int4 index within row
            const ivec4* tp = (const ivec4*)(targets + (size_t)a * NB + (b0 + 4 * t4));
            if (a < F_NORM) {
                v[j] = *tp;                              // LLC-resident rows
            } else {
                v[j] = __builtin_nontemporal_load(tp);   // streamed rows
            }
        }
        const float4* in4 = (const float4*)inputs + (size_t)b0 * 10;
        float4 xv[10];
        #pragma unroll
        for (int j = 0; j < 10; ++j) xv[j] = in4[t + TILE * j];

        // ---- pack labels -> LDS ----
        #pragma unroll
        for (int j = 0; j < 10; ++j) {
            const int q  = t + TILE * j;
            const int a  = q >> 6;
            const int t4 = q & 63;
            s_t[a * 65 + t4] =  (unsigned)(v[j].x & 1)        | ((unsigned)(v[j].y & 1) << 8)
                             | ((unsigned)(v[j].z & 1) << 16) | ((unsigned)(v[j].w & 1) << 24);
        }
        __syncthreads();

        // ---- compute ----
        const unsigned char* st8 = (const unsigned char*)s_t;
        #pragma unroll
        for (int j = 0; j < 10; ++j) {
            const int f = t + TILE * j;
            const int s = f / 10;            // sample within tile
            const int r = 4 * (f - s * 10);  // attr base (0,4,...,36)
            const float xs[4] = {xv[j].x, xv[j].y, xv[j].z, xv[j].w};
            #pragma unroll
            for (int k = 0; k < 4; ++k) {
                const float x   = xs[k];
                const float om  = 1.0f - x;
                const float w   = s_aw[r + k] * (om * om);   // -ln2/40*aw*(1-x)^2
                const float p   = fmaxf(x,  1e-12f);
                const float q0  = fmaxf(om, 1e-12f);
                const float sel = st8[(r + k) * 260 + s] ? p : q0;
                acc = fmaf(w, __log2f(sel), acc);            // w<0, log2<=0 -> positive
            }
        }
    } else {
        // ================= tail block (64 valid samples): guarded ===========
        #pragma unroll
        for (int j = 0; j < 10; ++j) {
            const int q  = t + TILE * j;
            const int a  = q >> 6;
            const int t4 = q & 63;
            const int base = b0 + 4 * t4;
            unsigned int pack = 0;
            for (int k = 0; k < 4; ++k)
                if (base + k < NB)
                    pack |= (unsigned)(targets[(size_t)a * NB + base + k] & 1) << (8 * k);
            s_t[a * 65 + t4] = pack;
        }
        __syncthreads();
        const unsigned char* st8 = (const unsigned char*)s_t;
        const float4* in4 = (const float4*)inputs + (size_t)b0 * 10;
        #pragma unroll
        for (int j = 0; j < 10; ++j) {
            const int f = t + TILE * j;
            const int s = f / 10;
            const int r = 4 * (f - s * 10);
            if (b0 + s < NB) {
                const float4 x4 = in4[f];
                const float xs[4] = {x4.x, x4.y, x4.z, x4.w};
                #pragma unroll
                for (int k = 0; k < 4; ++k) {
                    const float x   = xs[k];
                    const float om  = 1.0f - x;
                    const float w   = s_aw[r + k] * (om * om);
                    const float p   = fmaxf(x,  1e-12f);
                    const float q0  = fmaxf(om, 1e-12f);
                    const float sel = st8[(r + k) * 260 + s] ? p : q0;
                    acc = fmaf(w, __log2f(sel), acc);
                }
            }
        }
    }

    // ---- reduce: 64-lane shuffle -> cross-wave LDS -> one atomic/block ----
    float vsum = acc;
    #pragma unroll
    for (int off = 32; off > 0; off >>= 1)
        vsum += __shfl_xor(vsum, off, 64);
    if ((t & 63) == 0) s_red[t >> 6] = vsum;
    __syncthreads();
    if (t == 0) {
        float r2 = 0.0f;
        #pragma unroll
        for (int w2 = 0; w2 < TILE / 64; ++w2) r2 += s_red[w2];
        atomicAdd(out, r2);
    }
}

extern "C" void kernel_launch(void* const* d_in, const int* in_sizes, int n_in,
                              void* d_out, int out_size, void* d_ws, size_t ws_size,
                              hipStream_t stream) {
    const float* inputs  = (const float*)d_in[0];
    const int*   targets = (const int*)d_in[1];
    const float* attr_w  = (const float*)d_in[2];
    float* out = (float*)d_out;
    hipMemsetAsync(out, 0, sizeof(float), stream);
    focal_loss_kernel<<<dim3(NTILES), dim3(TILE), 0, stream>>>(inputs, targets, attr_w, out);
}

// Round 12
// 314.934 us; speedup vs baseline: 1.0131x; 1.0131x over previous
//
#include <hip/hip_runtime.h>

#define NB 1000000
#define NA 40
#define TILE 256
#define NTILES ((NB + TILE - 1) / TILE)   // 3907
#define NEG_LN2_OVER_A (-0.017328679513998632f)  // -ln(2)/40, folded into weights

// R12: nt-BOTH discriminator on the R10 base (93.9 us best-verified).
// R11 (partial-normal targets) REGRESSED to 105.3 us with FETCH unchanged at
// 160 MB: non-nt target rows still miss to HBM but now allocate in the MALL,
// churning inputs residency -> the MALL-hit path is the straggler; HBM has
// headroom. Rival hypothesis: ALL 320 MB traverses the L2->EA read path
// (3.44 TB/s at 93 us) and THAT is the cap — composition irrelevant.
// This round: __builtin_nontemporal_load on BOTH arrays -> all 320 MB HBM,
// MALL out of the equation, EA traffic unchanged.
//   H-A EA-read cap:   FETCH -> ~320 MB, dur 92-97 -> ROOFLINE at 93 (R10).
//   H-C separate caps: dur 55-75 us -> new regime, rebalance further.
//   H-B nt-path cap:   dur ~140-165 -> restore R10, ROOFLINE at 93.
// Only change vs R10: inputs loads are now nontemporal too.
typedef int   ivec4 __attribute__((ext_vector_type(4)));
typedef float fvec4 __attribute__((ext_vector_type(4)));

__global__ __launch_bounds__(256, 8) void focal_loss_kernel(
    const float* __restrict__ inputs,    // [NB, NA] f32
    const int*   __restrict__ targets,   // [NA, NB] i32 in {0,1}
    const float* __restrict__ attr_w,    // [NA] f32
    float* __restrict__ out)             // [1] f32 (pre-zeroed)
{
    __shared__ unsigned int s_t[NA * 65];      // [40][65] u32 = [40][260] bytes
    __shared__ float s_aw[NA];
    __shared__ float s_red[TILE / 64];

    const int t  = threadIdx.x;
    const int b0 = blockIdx.x * TILE;

    if (t < NA) s_aw[t] = attr_w[t] * NEG_LN2_OVER_A;

    float acc = 0.0f;

    if (blockIdx.x != NTILES - 1) {
        // ================= fast path: full tile, no per-element guards ======
        ivec4 v[10];
        #pragma unroll
        for (int j = 0; j < 10; ++j) {
            const int q  = t + TILE * j;   // [0, 2560)
            const int a  = q >> 6;         // attr 0..39
            const int t4 = q & 63;         // int4 index within row
            v[j] = __builtin_nontemporal_load(
                       (const ivec4*)(targets + (size_t)a * NB + (b0 + 4 * t4)));
        }
        const fvec4* in4 = (const fvec4*)inputs + (size_t)b0 * 10;
        fvec4 xv[10];
        #pragma unroll
        for (int j = 0; j < 10; ++j)
            xv[j] = __builtin_nontemporal_load(in4 + t + TILE * j);

        // ---- pack labels -> LDS ----
        #pragma unroll
        for (int j = 0; j < 10; ++j) {
            const int q  = t + TILE * j;
            const int a  = q >> 6;
            const int t4 = q & 63;
            s_t[a * 65 + t4] =  (unsigned)(v[j].x & 1)        | ((unsigned)(v[j].y & 1) << 8)
                             | ((unsigned)(v[j].z & 1) << 16) | ((unsigned)(v[j].w & 1) << 24);
        }
        __syncthreads();

        // ---- compute ----
        const unsigned char* st8 = (const unsigned char*)s_t;
        #pragma unroll
        for (int j = 0; j < 10; ++j) {
            const int f = t + TILE * j;
            const int s = f / 10;            // sample within tile
            const int r = 4 * (f - s * 10);  // attr base (0,4,...,36)
            const float xs[4] = {xv[j].x, xv[j].y, xv[j].z, xv[j].w};
            #pragma unroll
            for (int k = 0; k < 4; ++k) {
                const float x   = xs[k];
                const float om  = 1.0f - x;
                const float w   = s_aw[r + k] * (om * om);   // -ln2/40*aw*(1-x)^2
                const float p   = fmaxf(x,  1e-12f);
                const float q0  = fmaxf(om, 1e-12f);
                const float sel = st8[(r + k) * 260 + s] ? p : q0;
                acc = fmaf(w, __log2f(sel), acc);            // w<0, log2<=0 -> positive
            }
        }
    } else {
        // ================= tail block (64 valid samples): guarded ===========
        #pragma unroll
        for (int j = 0; j < 10; ++j) {
            const int q  = t + TILE * j;
            const int a  = q >> 6;
            const int t4 = q & 63;
            const int base = b0 + 4 * t4;
            unsigned int pack = 0;
            for (int k = 0; k < 4; ++k)
                if (base + k < NB)
                    pack |= (unsigned)(targets[(size_t)a * NB + base + k] & 1) << (8 * k);
            s_t[a * 65 + t4] = pack;
        }
        __syncthreads();
        const unsigned char* st8 = (const unsigned char*)s_t;
        const float4* in4 = (const float4*)inputs + (size_t)b0 * 10;
        #pragma unroll
        for (int j = 0; j < 10; ++j) {
            const int f = t + TILE * j;
            const int s = f / 10;
            const int r = 4 * (f - s * 10);
            if (b0 + s < NB) {
                const float4 x4 = in4[f];
                const float xs[4] = {x4.x, x4.y, x4.z, x4.w};
                #pragma unroll
                for (int k = 0; k < 4; ++k) {
                    const float x   = xs[k];
                    const float om  = 1.0f - x;
                    const float w   = s_aw[r + k] * (om * om);
                    const float p   = fmaxf(x,  1e-12f);
                    const float q0  = fmaxf(om, 1e-12f);
                    const float sel = st8[(r + k) * 260 + s] ? p : q0;
                    acc = fmaf(w, __log2f(sel), acc);
                }
            }
        }
    }

    // ---- reduce: 64-lane shuffle -> cross-wave LDS -> one atomic/block ----
    float vsum = acc;
    #pragma unroll
    for (int off = 32; off > 0; off >>= 1)
        vsum += __shfl_xor(vsum, off, 64);
    if ((t & 63) == 0) s_red[t >> 6] = vsum;
    __syncthreads();
    if (t == 0) {
        float r2 = 0.0f;
        #pragma unroll
        for (int w2 = 0; w2 < TILE / 64; ++w2) r2 += s_red[w2];
        atomicAdd(out, r2);
    }
}

extern "C" void kernel_launch(void* const* d_in, const int* in_sizes, int n_in,
                              void* d_out, int out_size, void* d_ws, size_t ws_size,
                              hipStream_t stream) {
    const float* inputs  = (const float*)d_in[0];
    const int*   targets = (const int*)d_in[1];
    const float* attr_w  = (const float*)d_in[2];
    float* out = (float*)d_out;
    hipMemsetAsync(out, 0, sizeof(float), stream);
    focal_loss_kernel<<<dim3(NTILES), dim3(TILE), 0, stream>>>(inputs, targets, attr_w, out);
}